// Round 5
// baseline (422.392 us; speedup 1.0000x reference)
//
#include <hip/hip_runtime.h>
#include <hip/hip_bf16.h>
#include <cstdint>

// ---------------------------------------------------------------------------
// Sampled DCT2: (1) luminance + per-8x8-block 2D DCT -> [64,1,512,512]
//               (2) exact JAX threefry permutation sampling -> [64,64,250]
//
// JAX PRNG semantics: jax_threefry_partitionable = True
//   split(key, n):   keys[i] = threefry(key, (0, i))
//   random_bits(subkey, 32, (n,)): bits[j] = o0 ^ o1 of threefry(subkey,(0,j))
//   permutation = 2 rounds of {key,sub = split(key); bits = random_bits(sub);
//       x = stable_sort_by(bits, x)}
//
// R9 (this round): heterogeneous fusion. dct (memory-bound, ~4 us total VALU)
// and sample-select (VALU-bound, <5% HBM) previously serialized on-stream.
// One kernel, grid 8192x512: even blockIdx -> sample-select (gb=blk>>1),
// odd -> two dct strips. Branch is WG-uniform (barrier-safe); co-resident
// WGs overlap the two pipes (time ~ max, not sum). The gather hazard
// (sample reads dct output at random blocks) is broken by writing 250
// absolute img offsets per gb to d_ws (within-launch lifetime; harness
// poison between iterations is harmless) and gathering in a trailing
// micro-kernel (img is L3-warm, ~67 MB).
//
// Sample algorithm (verified, bit-exact): inverse-select. Build per round a
// top-12-bit counting structure (scatter of (low20<<12|idx) packs; u32
// compare = exact stable tie-break); select(s) = element at sorted position
// s via binary search of inclusive ends + k-th-smallest of its (avg len 1)
// run. final[s] = select0(select1(s)).
// R3 lesson: generic rotl -> compiler picks v_alignbit (vector) / SALU
// (uniform); do NOT force the VALU builtin.
// ---------------------------------------------------------------------------

#define BATCH 64
#define HW 512
#define NBLK 4096
#define NSAMPLE 250
#define IMG_ELEMS (HW * HW)

#define A0 0.35355339059327373f
#define A1 0.49039264020161522f
#define A2 0.46193976625564337f
#define A3 0.41573480615127262f
#define A4 0.35355339059327379f
#define A5 0.27778511650980111f
#define A6 0.19134171618254492f
#define A7 0.09754516100806412f

__constant__ float Qc[8][8] = {
    { A0,  A0,  A0,  A0,  A0,  A0,  A0,  A0},
    { A1,  A3,  A5,  A7, -A7, -A5, -A3, -A1},
    { A2,  A6, -A6, -A2, -A2, -A6,  A6,  A2},
    { A3, -A7, -A1, -A5,  A5,  A1,  A7, -A3},
    { A4, -A4, -A4,  A4,  A4, -A4, -A4,  A4},
    { A5, -A1,  A7,  A3, -A3, -A7,  A1, -A5},
    { A6, -A2,  A2, -A6, -A6,  A2, -A2,  A6},
    { A7, -A5,  A3, -A1,  A1, -A3,  A5, -A7},
};

__constant__ int ZIGZAG[64] = {
    0, 1, 8, 16, 9, 2, 3, 10, 17, 24, 32, 25, 18, 11, 4, 5,
    12, 19, 26, 33, 40, 48, 41, 34, 27, 20, 13, 6, 7, 14, 21, 28,
    35, 42, 49, 56, 57, 50, 43, 36, 29, 22, 15, 23, 30, 37, 44, 51,
    58, 59, 52, 45, 38, 31, 39, 46, 53, 60, 61, 54, 47, 55, 62, 63
};

// ---------------- Threefry-2x32 (exact JAX rounds) -------------------------
__device__ __forceinline__ uint32_t rotl32(uint32_t v, int d) {
    return (v << d) | (v >> (32 - d));
}

__device__ __forceinline__ void tf2x32(uint32_t k0, uint32_t k1,
                                       uint32_t x0, uint32_t x1,
                                       uint32_t& o0, uint32_t& o1) {
    uint32_t ks0 = k0, ks1 = k1, ks2 = k0 ^ k1 ^ 0x1BD11BDAu;
    x0 += ks0; x1 += ks1;
#define TF_R(r) { x0 += x1; x1 = rotl32(x1, r); x1 ^= x0; }
    TF_R(13) TF_R(15) TF_R(26) TF_R(6)
    x0 += ks1; x1 += ks2 + 1u;
    TF_R(17) TF_R(29) TF_R(16) TF_R(24)
    x0 += ks2; x1 += ks0 + 2u;
    TF_R(13) TF_R(15) TF_R(26) TF_R(6)
    x0 += ks0; x1 += ks1 + 3u;
    TF_R(17) TF_R(29) TF_R(16) TF_R(24)
    x0 += ks1; x1 += ks2 + 4u;
    TF_R(13) TF_R(15) TF_R(26) TF_R(6)
    x0 += ks2; x1 += ks0 + 5u;
#undef TF_R
    o0 = x0; o1 = x1;
}

// ---------------- bucket-sorted structure over 4096 random keys ------------
__device__ __forceinline__ void build4096(
    uint32_t s0, uint32_t s1,
    uint32_t* __restrict__ pack32, uint32_t* __restrict__ hist32,
    int tid, int w, int lane, uint32_t* __restrict__ wsum) {
    uint16_t* hist16 = (uint16_t*)hist32;

    __syncthreads();  // prior-phase readers of pack/hist are done
#pragma unroll
    for (int q = 0; q < 4; ++q) hist32[tid + q * 512] = 0u;
    // key generation overlaps the zeroing stores
    uint32_t keys[8];
#pragma unroll
    for (int e = 0; e < 8; ++e) {
        uint32_t o0, o1;
        tf2x32(s0, s1, 0u, (uint32_t)(tid + e * 512), o0, o1);
        keys[e] = o0 ^ o1;
    }
    __syncthreads();

    // histogram; atomic return value = intra-bucket arrival order
    uint32_t ord[8];
#pragma unroll
    for (int e = 0; e < 8; ++e) {
        uint32_t bkt = keys[e] >> 20;
        uint32_t sh = (bkt & 1) << 4;
        uint32_t old = atomicAdd(&hist32[bkt >> 1], 1u << sh);
        ord[e] = (old >> sh) & 0xFFFFu;
    }
    __syncthreads();

    // prefix sum -> INCLUSIVE ends, in place (thread owns bins 8t..8t+7)
    uint4 wv = ((const uint4*)hist32)[tid];
    uint32_t c0 = wv.x & 0xFFFFu, c1 = wv.x >> 16;
    uint32_t c2 = wv.y & 0xFFFFu, c3 = wv.y >> 16;
    uint32_t c4 = wv.z & 0xFFFFu, c5 = wv.z >> 16;
    uint32_t c6 = wv.w & 0xFFFFu, c7 = wv.w >> 16;
    uint32_t ssum = c0 + c1 + c2 + c3 + c4 + c5 + c6 + c7;
    uint32_t sc = ssum;
#pragma unroll
    for (int off = 1; off < 64; off <<= 1) {
        uint32_t t = __shfl_up(sc, off);
        if (lane >= off) sc += t;
    }
    if (lane == 63) wsum[w] = sc;
    __syncthreads();
    uint32_t ex = sc - ssum;
    for (int ww = 0; ww < w; ++ww) ex += wsum[ww];
    uint32_t p1 = ex + c0, p2 = p1 + c1, p3 = p2 + c2, p4 = p3 + c3;
    uint32_t p5 = p4 + c4, p6 = p5 + c5, p7 = p6 + c6, p8 = p7 + c7;
    uint4 ov;
    ov.x = p1 | (p2 << 16); ov.y = p3 | (p4 << 16);
    ov.z = p5 | (p6 << 16); ov.w = p7 | (p8 << 16);
    ((uint4*)hist32)[tid] = ov;   // thread-local words: no cross-thread hazard
    __syncthreads();

    // scatter (plain write; position = bucket start + arrival order)
#pragma unroll
    for (int e = 0; e < 8; ++e) {
        uint32_t bkt = keys[e] >> 20;
        uint32_t start = bkt ? (uint32_t)hist16[bkt - 1] : 0u;
        pack32[start + ord[e]] =
            ((keys[e] & 0xFFFFFu) << 12) | (uint32_t)(tid + e * 512);
    }
}

// select: element index at sorted position s. Binary search inclusive ends
// (hist16[4095] == 4096 > s always), then k-th smallest of the run.
__device__ __forceinline__ uint32_t select4096(
    const uint16_t* __restrict__ hist16, const uint32_t* __restrict__ pack32,
    uint32_t s) {
    uint32_t lo = 0, hi = 4095;
#pragma unroll
    for (int it = 0; it < 12; ++it) {
        uint32_t mid = (lo + hi) >> 1;
        if ((uint32_t)hist16[mid] > s) hi = mid; else lo = mid + 1;
    }
    uint32_t b = lo;  // == hi: bucket containing position s
    uint32_t start = b ? (uint32_t)hist16[b - 1] : 0u;
    uint32_t L = (uint32_t)hist16[b] - start;
    uint32_t c = pack32[start];
    if (L > 1) {
        uint32_t k = s - start;
        for (uint32_t cand = 0; cand < L; ++cand) {
            uint32_t cc = pack32[start + cand];
            uint32_t cnt = 0;
            for (uint32_t o = 0; o < L; ++o)
                cnt += (pack32[start + o] < cc) ? 1u : 0u;
            if (cnt == k) { c = cc; break; }
        }
    }
    return c & 0xFFFu;
}

// ---------------- Fused kernel: dct strips | sample-select -----------------
// even blockIdx -> sample-select for gb = blockIdx>>1 (writes 250 img
// offsets to ws); odd blockIdx -> two 8x256 dct strips (t<256 / t>=256).
__global__ __launch_bounds__(512) void fused_kernel(const float* __restrict__ x,
                                                    float* __restrict__ out,
                                                    uint32_t* __restrict__ ws) {
    __shared__ __align__(16) uint8_t smem[25088];  // union of both paths
    __shared__ uint32_t wsum[8];

    const int tid = threadIdx.x;

    if (blockIdx.x & 1) {
        // =================== dct path: two strips ===================
        float* ylds = (float*)smem + (tid >> 8) * 2048;  // 8 KB per half
        const int t = tid & 255;
        const int wg = ((int)blockIdx.x & ~1) | (tid >> 8);  // 0..8191
        const int b = wg >> 7;
        const int ai = (wg >> 1) & 63;
        const int h = wg & 1;
        const int row0 = ai * 8;
        const int colbase = h * 256;

        {
            const int k = t >> 5;
            const int cg = t & 31;
            size_t off = (size_t)b * 3 * IMG_ELEMS + (size_t)(row0 + k) * HW +
                         colbase + cg * 8;
            float4 r0 = *(const float4*)(x + off);
            float4 r1 = *(const float4*)(x + off + 4);
            float4 g0 = *(const float4*)(x + off + IMG_ELEMS);
            float4 g1 = *(const float4*)(x + off + IMG_ELEMS + 4);
            float4 b0 = *(const float4*)(x + off + 2 * IMG_ELEMS);
            float4 b1 = *(const float4*)(x + off + 2 * IMG_ELEMS + 4);
            float R[8] = {r0.x, r0.y, r0.z, r0.w, r1.x, r1.y, r1.z, r1.w};
            float G[8] = {g0.x, g0.y, g0.z, g0.w, g1.x, g1.y, g1.z, g1.w};
            float B[8] = {b0.x, b0.y, b0.z, b0.w, b1.x, b1.y, b1.z, b1.w};
#pragma unroll
            for (int jj = 0; jj < 8; ++jj) {
                float y = (0.299f * (R[jj] * 255.0f) + 0.587f * (G[jj] * 255.0f) +
                           0.114f * (B[jj] * 255.0f)) / 255.0f;
                ylds[k * 256 + jj * 32 + cg] = y;  // bank = cg: 2-way (free)
            }
        }
        __syncthreads();

        const int i = t >> 5;
        const int bi = t & 31;
        float qrow[8];
#pragma unroll
        for (int k = 0; k < 8; ++k) qrow[k] = Qc[i][k];

        float acc[8];
#pragma unroll
        for (int j = 0; j < 8; ++j) acc[j] = 0.0f;
#pragma unroll
        for (int k = 0; k < 8; ++k) {
#pragma unroll
            for (int j = 0; j < 8; ++j)
                acc[j] += qrow[k] * ylds[k * 256 + j * 32 + bi];
        }

        float d[8];
#pragma unroll
        for (int j = 0; j < 8; ++j) {
            float s = 0.0f;
#pragma unroll
            for (int k = 0; k < 8; ++k) s += acc[k] * Qc[j][k];
            d[j] = s;
        }
        float4* o = (float4*)(out + (size_t)b * IMG_ELEMS +
                              (size_t)(row0 + i) * HW + colbase + bi * 8);
        o[0] = make_float4(d[0], d[1], d[2], d[3]);
        o[1] = make_float4(d[4], d[5], d[6], d[7]);
    } else {
        // =================== sample-select path ===================
        uint32_t* pack32 = (uint32_t*)smem;                    // 16 KB
        uint32_t* hist32 = (uint32_t*)(smem + 16384);          // 8 KB
        uint16_t* jsel = (uint16_t*)(smem + 24576);            // 512 B
        uint16_t* hist16 = (uint16_t*)hist32;

        const int w = tid >> 6;
        const int lane = tid & 63;
        const int gb = (int)blockIdx.x >> 1;  // b*64 + c

        uint32_t k0, k1, n0, n1, sA0, sA1, sB0, sB1;
        tf2x32(0u, 0u, 0u, (uint32_t)gb, k0, k1);
        tf2x32(k0, k1, 0u, 0u, n0, n1);     // key after round 0
        tf2x32(k0, k1, 0u, 1u, sA0, sA1);   // round-0 subkey
        tf2x32(n0, n1, 0u, 1u, sB0, sB1);   // round-1 subkey

        // round 1: j_s = element at sorted position s (s < 250)
        build4096(sB0, sB1, pack32, hist32, tid, w, lane, wsum);
        __syncthreads();
        if (tid < NSAMPLE)
            jsel[tid] = (uint16_t)select4096(hist16, pack32, (uint32_t)tid);
        // build4096's leading __syncthreads orders select reads before zeroing

        // round 0: i = element at sorted position j_s; emit img offset
        build4096(sA0, sA1, pack32, hist32, tid, w, lane, wsum);
        __syncthreads();

        int b = gb >> 6, c = gb & 63;
        int z = ZIGZAG[c];
        int i0z = z >> 3, j0z = z & 7;
        if (tid < NSAMPLE) {
            uint32_t i = select4096(hist16, pack32, (uint32_t)jsel[tid]);
            int ai = (int)i >> 6, bi = (int)i & 63;
            ws[(size_t)gb * 256 + tid] =
                (uint32_t)((size_t)b * IMG_ELEMS +
                           (size_t)(ai * 8 + i0z) * HW + (bi * 8 + j0z));
        }
    }
}

// ---------------- gather: out2[gb,s] = img[ws[gb,s]] -----------------------
// img is L2/L3-warm (67 MB just written). Coalesced ws reads + out writes.
__global__ __launch_bounds__(256) void gather_kernel(
    const float* __restrict__ img, const uint32_t* __restrict__ ws,
    float* __restrict__ out2) {
    const int gb = blockIdx.x;
    const int s = threadIdx.x;
    if (s < NSAMPLE)
        out2[(size_t)gb * NSAMPLE + s] = img[ws[(size_t)gb * 256 + s]];
}

extern "C" void kernel_launch(void* const* d_in, const int* in_sizes, int n_in,
                              void* d_out, int out_size, void* d_ws, size_t ws_size,
                              hipStream_t stream) {
    const float* x = (const float*)d_in[0];
    float* out = (float*)d_out;
    uint32_t* ws = (uint32_t*)d_ws;
    fused_kernel<<<BATCH * 128, 512, 0, stream>>>(x, out, ws);
    gather_kernel<<<BATCH * 64, 256, 0, stream>>>(
        out, ws, out + (size_t)BATCH * IMG_ELEMS);
}

// Round 6
// 387.335 us; speedup vs baseline: 1.0905x; 1.0905x over previous
//
#include <hip/hip_runtime.h>
#include <hip/hip_bf16.h>
#include <cstdint>

// ---------------------------------------------------------------------------
// Sampled DCT2: (1) luminance + per-8x8-block 2D DCT -> [64,1,512,512]
//               (2) exact JAX threefry permutation sampling -> [64,64,250]
//
// R10: fusion v2. R5's fused regression (214 us, VALUBusy 95->57%,
// occupancy 62->43%) is attributed to the dct path's LDS+barrier structure
// contending with sample's DS-pipe critical path (atomics-with-return, u16
// reads). This version's dct path has ZERO LDS and ZERO barriers: one
// thread per 8x8 block, computed in two row-halves (acc[4][8] = 32 regs;
// Y re-read per half -- input is L3-resident, R5 FETCH_SIZE showed 98 MB
// for a 201 MB input). k-loop rolled: dct waves may stall on HBM latency;
// co-resident VALU-bound sample waves hide it (that is the point of the
// fusion). __launch_bounds__(512,8) pins VGPR <= 64 so the fused kernel
// keeps sample's 4 WG/CU occupancy.
// Pre-committed: fused >= 180 us => abandon fusion, revert to serial R4.
//
// Sample algorithm (verified bit-exact): inverse-select over two counting
// builds; select(s) = binary search of inclusive ends + k-th smallest of
// the (avg len 1) bucket run; final[s] = select0(select1(s)). Writes 250
// absolute img offsets to ws; trailing gather kernel resolves them (breaks
// the dct->sample data hazard without a grid sync).
// R3 lesson: generic rotl -> compiler picks v_alignbit / SALU; don't force.
// ---------------------------------------------------------------------------

#define BATCH 64
#define HW 512
#define NBLK 4096
#define NSAMPLE 250
#define IMG_ELEMS (HW * HW)

#define A0 0.35355339059327373f
#define A1 0.49039264020161522f
#define A2 0.46193976625564337f
#define A3 0.41573480615127262f
#define A4 0.35355339059327379f
#define A5 0.27778511650980111f
#define A6 0.19134171618254492f
#define A7 0.09754516100806412f

__constant__ float Qc[8][8] = {
    { A0,  A0,  A0,  A0,  A0,  A0,  A0,  A0},
    { A1,  A3,  A5,  A7, -A7, -A5, -A3, -A1},
    { A2,  A6, -A6, -A2, -A2, -A6,  A6,  A2},
    { A3, -A7, -A1, -A5,  A5,  A1,  A7, -A3},
    { A4, -A4, -A4,  A4,  A4, -A4, -A4,  A4},
    { A5, -A1,  A7,  A3, -A3, -A7,  A1, -A5},
    { A6, -A2,  A2, -A6, -A6,  A2, -A2,  A6},
    { A7, -A5,  A3, -A1,  A1, -A3,  A5, -A7},
};

__constant__ int ZIGZAG[64] = {
    0, 1, 8, 16, 9, 2, 3, 10, 17, 24, 32, 25, 18, 11, 4, 5,
    12, 19, 26, 33, 40, 48, 41, 34, 27, 20, 13, 6, 7, 14, 21, 28,
    35, 42, 49, 56, 57, 50, 43, 36, 29, 22, 15, 23, 30, 37, 44, 51,
    58, 59, 52, 45, 38, 31, 39, 46, 53, 60, 61, 54, 47, 55, 62, 63
};

// ---------------- Threefry-2x32 (exact JAX rounds) -------------------------
__device__ __forceinline__ uint32_t rotl32(uint32_t v, int d) {
    return (v << d) | (v >> (32 - d));
}

__device__ __forceinline__ void tf2x32(uint32_t k0, uint32_t k1,
                                       uint32_t x0, uint32_t x1,
                                       uint32_t& o0, uint32_t& o1) {
    uint32_t ks0 = k0, ks1 = k1, ks2 = k0 ^ k1 ^ 0x1BD11BDAu;
    x0 += ks0; x1 += ks1;
#define TF_R(r) { x0 += x1; x1 = rotl32(x1, r); x1 ^= x0; }
    TF_R(13) TF_R(15) TF_R(26) TF_R(6)
    x0 += ks1; x1 += ks2 + 1u;
    TF_R(17) TF_R(29) TF_R(16) TF_R(24)
    x0 += ks2; x1 += ks0 + 2u;
    TF_R(13) TF_R(15) TF_R(26) TF_R(6)
    x0 += ks0; x1 += ks1 + 3u;
    TF_R(17) TF_R(29) TF_R(16) TF_R(24)
    x0 += ks1; x1 += ks2 + 4u;
    TF_R(13) TF_R(15) TF_R(26) TF_R(6)
    x0 += ks2; x1 += ks0 + 5u;
#undef TF_R
    o0 = x0; o1 = x1;
}

// ---------------- bucket-sorted structure over 4096 random keys ------------
__device__ __forceinline__ void build4096(
    uint32_t s0, uint32_t s1,
    uint32_t* __restrict__ pack32, uint32_t* __restrict__ hist32,
    int tid, int w, int lane, uint32_t* __restrict__ wsum) {
    uint16_t* hist16 = (uint16_t*)hist32;

    __syncthreads();  // prior-phase readers of pack/hist are done
#pragma unroll
    for (int q = 0; q < 4; ++q) hist32[tid + q * 512] = 0u;
    // key generation overlaps the zeroing stores
    uint32_t keys[8];
#pragma unroll
    for (int e = 0; e < 8; ++e) {
        uint32_t o0, o1;
        tf2x32(s0, s1, 0u, (uint32_t)(tid + e * 512), o0, o1);
        keys[e] = o0 ^ o1;
    }
    __syncthreads();

    // histogram; atomic return value = intra-bucket arrival order
    uint32_t ord[8];
#pragma unroll
    for (int e = 0; e < 8; ++e) {
        uint32_t bkt = keys[e] >> 20;
        uint32_t sh = (bkt & 1) << 4;
        uint32_t old = atomicAdd(&hist32[bkt >> 1], 1u << sh);
        ord[e] = (old >> sh) & 0xFFFFu;
    }
    __syncthreads();

    // prefix sum -> INCLUSIVE ends, in place (thread owns bins 8t..8t+7)
    uint4 wv = ((const uint4*)hist32)[tid];
    uint32_t c0 = wv.x & 0xFFFFu, c1 = wv.x >> 16;
    uint32_t c2 = wv.y & 0xFFFFu, c3 = wv.y >> 16;
    uint32_t c4 = wv.z & 0xFFFFu, c5 = wv.z >> 16;
    uint32_t c6 = wv.w & 0xFFFFu, c7 = wv.w >> 16;
    uint32_t ssum = c0 + c1 + c2 + c3 + c4 + c5 + c6 + c7;
    uint32_t sc = ssum;
#pragma unroll
    for (int off = 1; off < 64; off <<= 1) {
        uint32_t t = __shfl_up(sc, off);
        if (lane >= off) sc += t;
    }
    if (lane == 63) wsum[w] = sc;
    __syncthreads();
    uint32_t ex = sc - ssum;
    for (int ww = 0; ww < w; ++ww) ex += wsum[ww];
    uint32_t p1 = ex + c0, p2 = p1 + c1, p3 = p2 + c2, p4 = p3 + c3;
    uint32_t p5 = p4 + c4, p6 = p5 + c5, p7 = p6 + c6, p8 = p7 + c7;
    uint4 ov;
    ov.x = p1 | (p2 << 16); ov.y = p3 | (p4 << 16);
    ov.z = p5 | (p6 << 16); ov.w = p7 | (p8 << 16);
    ((uint4*)hist32)[tid] = ov;   // thread-local words: no cross-thread hazard
    __syncthreads();

    // scatter (plain write; position = bucket start + arrival order)
#pragma unroll
    for (int e = 0; e < 8; ++e) {
        uint32_t bkt = keys[e] >> 20;
        uint32_t start = bkt ? (uint32_t)hist16[bkt - 1] : 0u;
        pack32[start + ord[e]] =
            ((keys[e] & 0xFFFFFu) << 12) | (uint32_t)(tid + e * 512);
    }
}

// select: element index at sorted position s. Binary search inclusive ends
// (hist16[4095] == 4096 > s always), then k-th smallest of the run.
__device__ __forceinline__ uint32_t select4096(
    const uint16_t* __restrict__ hist16, const uint32_t* __restrict__ pack32,
    uint32_t s) {
    uint32_t lo = 0, hi = 4095;
#pragma unroll
    for (int it = 0; it < 12; ++it) {
        uint32_t mid = (lo + hi) >> 1;
        if ((uint32_t)hist16[mid] > s) hi = mid; else lo = mid + 1;
    }
    uint32_t b = lo;  // == hi: bucket containing position s
    uint32_t start = b ? (uint32_t)hist16[b - 1] : 0u;
    uint32_t L = (uint32_t)hist16[b] - start;
    uint32_t c = pack32[start];
    if (L > 1) {
        uint32_t k = s - start;
        for (uint32_t cand = 0; cand < L; ++cand) {
            uint32_t cc = pack32[start + cand];
            uint32_t cnt = 0;
            for (uint32_t o = 0; o < L; ++o)
                cnt += (pack32[start + o] < cc) ? 1u : 0u;
            if (cnt == k) { c = cc; break; }
        }
    }
    return c & 0xFFFu;
}

// ---------------- Fused kernel: sample-select | LDS-free dct ---------------
// grid 4608 = 512 groups x 9. rem<8 -> sample gb = grp*8+rem (4096 WGs);
// rem==8 -> dct chunk = grp (512 WGs x 512 threads = one thread per 8x8
// block). dct path: no LDS, no barriers; 8x8 DCT in two row-halves
// (acc[4][8], Y re-read per half; input is L3-resident).
__global__ __launch_bounds__(512, 8) void fused_kernel(
    const float* __restrict__ x, float* __restrict__ out,
    uint32_t* __restrict__ ws) {
    __shared__ __align__(16) uint8_t smem[25088];  // sample path only
    __shared__ uint32_t wsum[8];

    const int tid = threadIdx.x;
    const int grp = (int)blockIdx.x / 9;
    const int rem = (int)blockIdx.x % 9;

    if (rem == 8) {
        // =================== dct path (no LDS, no barriers) ===============
        int g = grp * 512 + tid;            // one thread per 8x8 block
        int b = g >> 12;
        int rr = g & 4095;
        int ai = rr >> 6, bi = rr & 63;
        int row0 = ai * 8, col0 = bi * 8;
        size_t ib = (size_t)b * 3 * IMG_ELEMS;
        size_t ob = (size_t)b * IMG_ELEMS;

        for (int half = 0; half < 2; ++half) {
            float acc[4][8];  // rows half*4 .. half*4+3 of Q*Y
#pragma unroll
            for (int i2 = 0; i2 < 4; ++i2)
#pragma unroll
                for (int j = 0; j < 8; ++j) acc[i2][j] = 0.0f;

#pragma unroll 1
            for (int k = 0; k < 8; ++k) {
                size_t off = ib + (size_t)(row0 + k) * HW + col0;
                float y[8];
                {
                    float4 r0 = *(const float4*)(x + off);
                    float4 g0 = *(const float4*)(x + off + IMG_ELEMS);
                    float4 b0 = *(const float4*)(x + off + 2 * IMG_ELEMS);
                    y[0] = (0.299f * (r0.x * 255.0f) + 0.587f * (g0.x * 255.0f) +
                            0.114f * (b0.x * 255.0f)) / 255.0f;
                    y[1] = (0.299f * (r0.y * 255.0f) + 0.587f * (g0.y * 255.0f) +
                            0.114f * (b0.y * 255.0f)) / 255.0f;
                    y[2] = (0.299f * (r0.z * 255.0f) + 0.587f * (g0.z * 255.0f) +
                            0.114f * (b0.z * 255.0f)) / 255.0f;
                    y[3] = (0.299f * (r0.w * 255.0f) + 0.587f * (g0.w * 255.0f) +
                            0.114f * (b0.w * 255.0f)) / 255.0f;
                }
                {
                    float4 r1 = *(const float4*)(x + off + 4);
                    float4 g1 = *(const float4*)(x + off + IMG_ELEMS + 4);
                    float4 b1 = *(const float4*)(x + off + 2 * IMG_ELEMS + 4);
                    y[4] = (0.299f * (r1.x * 255.0f) + 0.587f * (g1.x * 255.0f) +
                            0.114f * (b1.x * 255.0f)) / 255.0f;
                    y[5] = (0.299f * (r1.y * 255.0f) + 0.587f * (g1.y * 255.0f) +
                            0.114f * (b1.y * 255.0f)) / 255.0f;
                    y[6] = (0.299f * (r1.z * 255.0f) + 0.587f * (g1.z * 255.0f) +
                            0.114f * (b1.z * 255.0f)) / 255.0f;
                    y[7] = (0.299f * (r1.w * 255.0f) + 0.587f * (g1.w * 255.0f) +
                            0.114f * (b1.w * 255.0f)) / 255.0f;
                }
#pragma unroll
                for (int i2 = 0; i2 < 4; ++i2) {
                    float q = Qc[half * 4 + i2][k];
#pragma unroll
                    for (int j = 0; j < 8; ++j) acc[i2][j] += q * y[j];
                }
            }

#pragma unroll
            for (int i2 = 0; i2 < 4; ++i2) {
                float d[8];
#pragma unroll
                for (int j = 0; j < 8; ++j) {
                    float s = 0.0f;
#pragma unroll
                    for (int k = 0; k < 8; ++k) s += acc[i2][k] * Qc[j][k];
                    d[j] = s;
                }
                float4* o = (float4*)(out + ob +
                                      (size_t)(row0 + half * 4 + i2) * HW + col0);
                o[0] = make_float4(d[0], d[1], d[2], d[3]);
                o[1] = make_float4(d[4], d[5], d[6], d[7]);
            }
        }
    } else {
        // =================== sample-select path ===========================
        uint32_t* pack32 = (uint32_t*)smem;                    // 16 KB
        uint32_t* hist32 = (uint32_t*)(smem + 16384);          // 8 KB
        uint16_t* jsel = (uint16_t*)(smem + 24576);            // 512 B
        uint16_t* hist16 = (uint16_t*)hist32;

        const int w = tid >> 6;
        const int lane = tid & 63;
        const int gb = grp * 8 + rem;  // b*64 + c

        uint32_t k0, k1, n0, n1, sA0, sA1, sB0, sB1;
        tf2x32(0u, 0u, 0u, (uint32_t)gb, k0, k1);
        tf2x32(k0, k1, 0u, 0u, n0, n1);     // key after round 0
        tf2x32(k0, k1, 0u, 1u, sA0, sA1);   // round-0 subkey
        tf2x32(n0, n1, 0u, 1u, sB0, sB1);   // round-1 subkey

        // round 1: j_s = element at sorted position s (s < 250)
        build4096(sB0, sB1, pack32, hist32, tid, w, lane, wsum);
        __syncthreads();
        if (tid < NSAMPLE)
            jsel[tid] = (uint16_t)select4096(hist16, pack32, (uint32_t)tid);
        // build4096's leading __syncthreads orders select reads before zeroing

        // round 0: i = element at sorted position j_s; emit img offset
        build4096(sA0, sA1, pack32, hist32, tid, w, lane, wsum);
        __syncthreads();

        int b = gb >> 6, c = gb & 63;
        int z = ZIGZAG[c];
        int i0z = z >> 3, j0z = z & 7;
        if (tid < NSAMPLE) {
            uint32_t i = select4096(hist16, pack32, (uint32_t)jsel[tid]);
            int ai = (int)i >> 6, bi = (int)i & 63;
            ws[(size_t)gb * 256 + tid] =
                (uint32_t)((size_t)b * IMG_ELEMS +
                           (size_t)(ai * 8 + i0z) * HW + (bi * 8 + j0z));
        }
    }
}

// ---------------- gather: out2[gb,s] = img[ws[gb,s]] -----------------------
__global__ __launch_bounds__(256) void gather_kernel(
    const float* __restrict__ img, const uint32_t* __restrict__ ws,
    float* __restrict__ out2) {
    const int gb = blockIdx.x;
    const int s = threadIdx.x;
    if (s < NSAMPLE)
        out2[(size_t)gb * NSAMPLE + s] = img[ws[(size_t)gb * 256 + s]];
}

extern "C" void kernel_launch(void* const* d_in, const int* in_sizes, int n_in,
                              void* d_out, int out_size, void* d_ws, size_t ws_size,
                              hipStream_t stream) {
    const float* x = (const float*)d_in[0];
    float* out = (float*)d_out;
    uint32_t* ws = (uint32_t*)d_ws;
    fused_kernel<<<512 * 9, 512, 0, stream>>>(x, out, ws);
    gather_kernel<<<BATCH * 64, 256, 0, stream>>>(
        out, ws, out + (size_t)BATCH * IMG_ELEMS);
}